// Round 5
// baseline (150.518 us; speedup 1.0000x reference)
//
#include <hip/hip_runtime.h>

#define EXTENT 7
#define CHANNELS 256
#define NPTS (EXTENT * EXTENT)  // 49

typedef float v4f __attribute__((ext_vector_type(4)));

// ---------------------------------------------------------------------------
// R6: row-major contiguous point runs (DRAM run-length fix).
// Evidence trail: per-wave MLP (R1), occupancy (R0/R1), LLC prime (R3), and
// footprint concentration via sorted windows (R4) were ALL null — the kernel
// sits at 3.4 TB/s no matter what. Remaining variable: sequential run length
// of the request streams. Old mapping (p = q*4+w + 16k) made each block read
// 6-8 different y-rows with scattered x simultaneously (pure 2KB-chunk
// shuffle at the controllers) and write at 16KB stride. New mapping: item q
// owns a CONTIGUOUS run of grid points (0-12 | 13-24 | 25-36 | 37-48), wave
// w takes p = base+w+4k issued ascending -> each block's reads form ~4
// ascending row-streams (open-row hits), writes one contiguous 12-13KB run.
// Sort pass dropped (R4: neutral, +2.5us).
// ---------------------------------------------------------------------------
__global__ __launch_bounds__(256) void roi_align_pyramid_kernel(
    const float* __restrict__ metadata,
    const float* __restrict__ boxes,
    const float* __restrict__ p2,
    const float* __restrict__ p3,
    const float* __restrict__ p4,
    const float* __restrict__ p5,
    float* __restrict__ out,
    int n_boxes)
{
    const int box = blockIdx.x % n_boxes;      // all 4 q-blocks of a box on
    const int q   = blockIdx.x / n_boxes;      // the same XCD (n_boxes%8==0)
    const int tid = threadIdx.x;
    const int w   = tid >> 6;                  // wave 0..3 (uniform per wave)
    const int c   = (tid & 63) << 2;           // channel offset

    // Contiguous point run for this item: lens {13,12,12,12}.
    const int base = (q == 0) ? 0 : (1 + 12 * q);   // 0,13,25,37
    const int len  = (q == 0) ? 13 : 12;

    const float rows = metadata[0];
    const float cols = metadata[1];

    const float x1 = boxes[box * 4 + 0];
    const float y1 = boxes[box * 4 + 1];
    const float x2 = boxes[box * 4 + 2];
    const float y2 = boxes[box * 4 + 3];

    // Level selection — replicate reference fp32 math.
    const float h = y2 - y1;
    const float w_ = x2 - x1;
    float roi_level = logf(sqrtf(h * w_) / sqrtf(rows * cols)) / logf(2.0f);
    roi_level = fminf(5.0f, fmaxf(2.0f, 4.0f + rintf(roi_level)));
    const int lvl = (int)roi_level;  // 2..5

    const float* feat;
    int H;
    if      (lvl == 2) { feat = p2; H = 256; }
    else if (lvl == 3) { feat = p3; H = 128; }
    else if (lvl == 4) { feat = p4; H = 64; }
    else               { feat = p5; H = 32; }
    const int W = H;
    const size_t rowstr = (size_t)W * CHANNELS;

    // Normalized box coords (tf.crop_and_resize convention).
    const float ny1 = y1 / (rows - 1.0f);
    const float ny2 = y2 / (rows - 1.0f);
    const float nx1 = x1 / (cols - 1.0f);
    const float nx2 = x2 / (cols - 1.0f);

    float* outp = out + (size_t)box * NPTS * CHANNELS + c;

    // Per-point address + weight computation.
    auto setup = [&](int p, const float*& bptr,
                     float& w00, float& w01, float& w10, float& w11) {
        const int gy = p / EXTENT;
        const int gx = p - gy * EXTENT;

        const float gyf = (float)gy / (float)(EXTENT - 1);
        const float ysv = (ny1 + (ny2 - ny1) * gyf) * (float)(H - 1);
        float y0f = floorf(ysv);
        y0f = fminf(fmaxf(y0f, 0.0f), (float)(H - 2));
        const int   y0 = (int)y0f;
        const float wy = ysv - y0f;

        const float gxf = (float)gx / (float)(EXTENT - 1);
        const float xsv = (nx1 + (nx2 - nx1) * gxf) * (float)(W - 1);
        float x0f = floorf(xsv);
        x0f = fminf(fmaxf(x0f, 0.0f), (float)(W - 2));
        const int   x0 = (int)x0f;
        const float wx = xsv - x0f;

        bptr = feat + ((size_t)(y0 * W + x0)) * CHANNELS + c;
        w00 = (1.0f - wy) * (1.0f - wx);
        w01 = (1.0f - wy) * wx;
        w10 = wy * (1.0f - wx);
        w11 = wy * wx;
    };

    // Wave w handles p = base + w + 4k, k ascending -> ascending addresses.
    // Guards are wave-uniform (w, len uniform), so no divergence.
    const float* bptr[4];
    float W00[4], W01[4], W10[4], W11[4];
    v4f f00[4], f01[4], f10[4], f11[4];

    #pragma unroll
    for (int k = 0; k < 4; ++k) {
        const int r = w + 4 * k;
        if (r < len) {
            setup(base + r, bptr[k], W00[k], W01[k], W10[k], W11[k]);
            f00[k] = *(const v4f*)(bptr[k]);
            f01[k] = *(const v4f*)(bptr[k] + CHANNELS);
            f10[k] = *(const v4f*)(bptr[k] + rowstr);
            f11[k] = *(const v4f*)(bptr[k] + rowstr + CHANNELS);
        }
    }

    #pragma unroll
    for (int k = 0; k < 4; ++k) {
        const int r = w + 4 * k;
        if (r < len) {
            v4f res = f00[k] * W00[k] + f01[k] * W01[k]
                    + f10[k] * W10[k] + f11[k] * W11[k];
            // Write-once data: nontemporal store keeps feature lines resident.
            __builtin_nontemporal_store(res,
                (v4f*)(outp + (size_t)(base + r) * CHANNELS));
        }
    }
}

extern "C" void kernel_launch(void* const* d_in, const int* in_sizes, int n_in,
                              void* d_out, int out_size, void* d_ws, size_t ws_size,
                              hipStream_t stream) {
    const float* metadata = (const float*)d_in[0];
    const float* boxes    = (const float*)d_in[1];
    const float* p2       = (const float*)d_in[2];
    const float* p3       = (const float*)d_in[3];
    const float* p4       = (const float*)d_in[4];
    const float* p5       = (const float*)d_in[5];
    float* out = (float*)d_out;

    const int n_boxes = in_sizes[1] / 4;  // 1024
    dim3 grid(n_boxes * 4);
    dim3 block(256);
    roi_align_pyramid_kernel<<<grid, block, 0, stream>>>(
        metadata, boxes, p2, p3, p4, p5, out, n_boxes);
}

// Round 6
// 144.149 us; speedup vs baseline: 1.0442x; 1.0442x over previous
//
#include <hip/hip_runtime.h>

#define EXTENT 7
#define CHANNELS 256
#define NPTS (EXTENT * EXTENT)  // 49

typedef float v4f __attribute__((ext_vector_type(4)));

// ---------------------------------------------------------------------------
// R7: R0 structure (the 42.8us best: VGPR=20, occ 61%) with ONE change —
// plain cached stores instead of __builtin_nontemporal_store.
// Rationale: 5 rounds proved the read stream is irreducible (compulsory 93MB
// in ~2KB bilinear-tap chunks; MLP/occupancy/priming/windowing/ordering all
// null). The write stream is the last untested variable: nt stores bypass
// the memory-side 256MB Infinity Cache and stream 50MB to DRAM DURING the
// kernel, interleaving write bursts (turnaround penalties) into the random
// read stream. Plain write-back stores let L3 absorb the output as dirty
// lines and write back lazily in scheduled batches. The original "keep
// feature lines resident" justification for nt is dead: FETCH==footprint,
// there is no reuse to protect (R3/R4).
// ---------------------------------------------------------------------------
// Grid = 4 * n_boxes. blockIdx = q*n_boxes + box (n_boxes % 8 == 0, so all 4
// sub-blocks of one box land on the same XCD under round-robin dispatch).
// 256 threads: (tid & 63) -> 4 channels via v4f (64 lanes x 16B = full 1KB
// channel row, coalesced); sub = q*4 + (tid>>6) in [0,16) -> 3-4 of the 49
// grid points per thread, fully unrolled.
__global__ __launch_bounds__(256) void roi_align_pyramid_kernel(
    const float* __restrict__ metadata,
    const float* __restrict__ boxes,
    const float* __restrict__ p2,
    const float* __restrict__ p3,
    const float* __restrict__ p4,
    const float* __restrict__ p5,
    float* __restrict__ out,
    int n_boxes)
{
    const int box = blockIdx.x % n_boxes;
    const int q   = blockIdx.x / n_boxes;      // 0..3
    const int tid = threadIdx.x;
    const int sub = (q << 2) | (tid >> 6);     // 0..15, uniform per wave
    const int c   = (tid & 63) << 2;           // channel offset

    const float rows = metadata[0];
    const float cols = metadata[1];

    const float x1 = boxes[box * 4 + 0];
    const float y1 = boxes[box * 4 + 1];
    const float x2 = boxes[box * 4 + 2];
    const float y2 = boxes[box * 4 + 3];

    // Level selection — replicate reference fp32 math.
    const float h = y2 - y1;
    const float w = x2 - x1;
    float roi_level = logf(sqrtf(h * w) / sqrtf(rows * cols)) / logf(2.0f);
    roi_level = fminf(5.0f, fmaxf(2.0f, 4.0f + rintf(roi_level)));
    const int lvl = (int)roi_level;  // 2..5

    const float* feat;
    int H;
    if      (lvl == 2) { feat = p2; H = 256; }
    else if (lvl == 3) { feat = p3; H = 128; }
    else if (lvl == 4) { feat = p4; H = 64; }
    else               { feat = p5; H = 32; }
    const int W = H;

    // Normalized box coords (tf.crop_and_resize convention).
    const float ny1 = y1 / (rows - 1.0f);
    const float ny2 = y2 / (rows - 1.0f);
    const float nx1 = x1 / (cols - 1.0f);
    const float nx2 = x2 / (cols - 1.0f);

    float* outp = out + (size_t)box * NPTS * CHANNELS + c;

    auto process = [&](int p) {
        const int gy = p / EXTENT;
        const int gx = p - gy * EXTENT;

        const float gyf = (float)gy / (float)(EXTENT - 1);
        const float ysv = (ny1 + (ny2 - ny1) * gyf) * (float)(H - 1);
        float y0f = floorf(ysv);
        y0f = fminf(fmaxf(y0f, 0.0f), (float)(H - 2));
        const int   y0 = (int)y0f;
        const float wy = ysv - y0f;

        const float gxf = (float)gx / (float)(EXTENT - 1);
        const float xsv = (nx1 + (nx2 - nx1) * gxf) * (float)(W - 1);
        float x0f = floorf(xsv);
        x0f = fminf(fmaxf(x0f, 0.0f), (float)(W - 2));
        const int   x0 = (int)x0f;
        const float wx = xsv - x0f;

        const float* base = feat + ((size_t)(y0 * W + x0)) * CHANNELS + c;
        const v4f f00 = *(const v4f*)(base);
        const v4f f01 = *(const v4f*)(base + CHANNELS);
        const v4f f10 = *(const v4f*)(base + (size_t)W * CHANNELS);
        const v4f f11 = *(const v4f*)(base + (size_t)W * CHANNELS + CHANNELS);

        const float w00 = (1.0f - wy) * (1.0f - wx);
        const float w01 = (1.0f - wy) * wx;
        const float w10 = wy * (1.0f - wx);
        const float w11 = wy * wx;

        v4f r = f00 * w00 + f01 * w01 + f10 * w10 + f11 * w11;

        // Plain cached store: let the memory-side Infinity Cache absorb the
        // output and write back lazily (R7 change — was nontemporal).
        *(v4f*)(outp + (size_t)p * CHANNELS) = r;
    };

    // 49 points: sub + 16k for k in [0,3) covers p in [0,48); p=48 by sub==0.
    #pragma unroll
    for (int k = 0; k < 3; ++k) {
        process(sub + 16 * k);
    }
    if (sub == 0) {
        process(48);
    }
}

extern "C" void kernel_launch(void* const* d_in, const int* in_sizes, int n_in,
                              void* d_out, int out_size, void* d_ws, size_t ws_size,
                              hipStream_t stream) {
    const float* metadata = (const float*)d_in[0];
    const float* boxes    = (const float*)d_in[1];
    const float* p2       = (const float*)d_in[2];
    const float* p3       = (const float*)d_in[3];
    const float* p4       = (const float*)d_in[4];
    const float* p5       = (const float*)d_in[5];
    float* out = (float*)d_out;

    const int n_boxes = in_sizes[1] / 4;  // 1024
    dim3 grid(n_boxes * 4);
    dim3 block(256);
    roi_align_pyramid_kernel<<<grid, block, 0, stream>>>(
        metadata, boxes, p2, p3, p4, p5, out, n_boxes);
}